// Round 7
// baseline (384.162 us; speedup 1.0000x reference)
//
#include <hip/hip_runtime.h>
#include <cstdint>
#include <cstddef>

// Shapes fixed by the reference harness.
#define MM 2048
#define KK 4096
#define NN 4096
#define GG 32   // K / 128 groups
#define BM 128
#define BN 256
#define BK 64
#define NTILES (KK / BK)   // 64 k-tiles

typedef _Float16 half8_t __attribute__((ext_vector_type(8)));
typedef float f32x4 __attribute__((ext_vector_type(4)));

// ---------------------------------------------------------------------------
// R13: single fused kernel, zero workspace, zero prep.
//
// WHY: (1) gemm at 80us == 860 TF == the documented ceiling of this structure
// class; the 256^2 8-phase escape is grid-starved at M=2048 (128 blocks on
// 256 CUs). (2) total - gemm has been a constant ~125us across six rounds --
// far more than prep's ~30us of real traffic -- and the one small-workspace
// round (R11, 32.5MB vs 48MB) showed the smallest residue. Hypothesis: the
// residue is prep dispatch + per-iteration workspace re-poison/memset cost,
// i.e. proportional to OUR footprint. This round removes prep and workspace
// entirely; the total either drops by the prep+poison component (win) or
// localizes the 125us as fixed harness cost (diagnosis).
//
// Structure: R7's verified consumer (128x256 block, 8 waves of 64x64, BK=64,
// XOR-swizzled LDS, 3-buffer rotation, 1 barrier/tile) with reg-staged
// producers replacing global_load_lds:
//   L(t): issue global loads for tile t (A fp32 x4 float4, B q int32 x8 int4,
//         scale/zero dwords) into a NAMED reg set (even/odd, rule #20).
//   W(t): cvt A fp32->f16; dequant B via f32 fmaf(q, s, -z*s) (numerically
//         identical to the verified prep kernel); ds_write_b128 into the
//         EXACT R7 LDS layout: phys 16B chunk = logical ^ (row & 7).
//   C(t): R7's verified frag reads + 32 MFMA + epilogue, unchanged.
// Pipeline: prologue L(0),W(0),L(1); iter t: C(t) | L(t+2) | W(t+1); barrier.
// Buf safety: W(t+1) writes buf[(t+1)%3], last read at C(t-2), barrier'd.
// Reg-set safety: L(tau) -> set[tau%2]; W(t+1) consumes set[(t+1)%2], loaded
// at iter t-1. No LDS DMA => the compiler's own precise counted vmcnt/lgkmcnt
// dependency ledger applies (no alias-conservative drains -- the R7/R8 trap).
//
// Producer/consumer layout proof (B): thread covers row rB=tid>>1, elems
// (tid&1)*32+[0..31]; write chunk j holds elems (tid&1)*32+8j.. => logical
// chunk lc=(tid&1)*4+j, stored at phys lc^(rB&7). Reader wants logical
// j8=ks*4+quad at phys j8^(row&7) -- same involution, rows congruent mod 8.
// A: row rA=tid>>2, elems (tid&3)*16+[0..15], lc=(tid&3)*2+j. Bank check:
// each b128 write distributes 8 lanes per 16B-position per pass = minimum
// passes, conflict-free (same distribution as the verified reads).
// ---------------------------------------------------------------------------
__global__ __launch_bounds__(512, 2)
void gemm_fused13(const float* __restrict__ Af, const int* __restrict__ qw,
                  const float* __restrict__ scales, const float* __restrict__ zeros,
                  const float* __restrict__ bias, float* __restrict__ out)
{
  __shared__ __align__(16) _Float16 sA[3][BM * BK];   // 3 x 16 KiB
  __shared__ __align__(16) _Float16 sB[3][BN * BK];   // 3 x 32 KiB  -> 144 KiB

  const int tid = threadIdx.x;
  const int lane = tid & 63;
  const int wave = tid >> 6;        // 0..7
  const int wr = wave >> 2;         // 0..1  (m-row of wave, 64 tall)
  const int wc = wave & 3;          // 0..3  (n-col of wave, 64 wide)
  const int lr = lane & 15, quad = lane >> 4;

  // XCD-aware swizzle: 256 blocks, 8 XCDs round-robin by bid.
  const int bid = blockIdx.x;
  const int xcd = bid & 7;
  const int slot = bid >> 3;        // 0..31
  const int mt = slot >> 1;         // 0..15
  const int nt = xcd * 2 + (slot & 1);
  const int m0 = mt * BM;
  const int n0 = nt * BN;

  // Producer geometry.
  const int arow = tid >> 2, aquad = tid & 3;   // A: 128 rows x 4 thr/row
  const int brow = tid >> 1, bhalf = tid & 1;   // B: 256 rows x 2 thr/row
  const size_t aBase = (size_t)(m0 + arow) * KK;
  const size_t bBase = (size_t)(n0 + brow) * KK;
  const int szBase = (n0 + brow) << 5;

  f32x4 acc[4][4];
#pragma unroll
  for (int i = 0; i < 4; ++i)
#pragma unroll
    for (int j = 0; j < 4; ++j) acc[i][j] = (f32x4){0.f, 0.f, 0.f, 0.f};

  // Named even/odd in-flight register sets (rule #20: no runtime indexing).
  float4 aR0[4], aR1[4];
  int4   bR0[8], bR1[8];
  float  sc0, nz0, sc1, nz1;

#define LOADSET(T, aR, bR, scR, nzR)                                            \
  do {                                                                          \
    const int k0_ = (T) * BK;                                                   \
    _Pragma("unroll")                                                           \
    for (int j = 0; j < 4; ++j)                                                 \
      aR[j] = *(const float4*)&Af[aBase + k0_ + aquad * 16 + j * 4];            \
    _Pragma("unroll")                                                           \
    for (int i = 0; i < 8; ++i)                                                 \
      bR[i] = *(const int4*)&qw[bBase + k0_ + bhalf * 32 + i * 4];              \
    const int g_ = (T) >> 1;                                                    \
    scR = scales[szBase + g_];                                                  \
    nzR = -zeros[szBase + g_] * scR;                                            \
  } while (0)

#define WRITESET(BUF, aR, bR, scR, nzR)                                         \
  do {                                                                          \
    _Pragma("unroll")                                                           \
    for (int j = 0; j < 2; ++j) {                                               \
      const float4 v0 = aR[2 * j], v1 = aR[2 * j + 1];                          \
      half8_t h;                                                                \
      h[0] = (_Float16)v0.x; h[1] = (_Float16)v0.y;                             \
      h[2] = (_Float16)v0.z; h[3] = (_Float16)v0.w;                             \
      h[4] = (_Float16)v1.x; h[5] = (_Float16)v1.y;                             \
      h[6] = (_Float16)v1.z; h[7] = (_Float16)v1.w;                             \
      *(half8_t*)&sA[BUF][arow * BK + (((aquad * 2 + j) ^ (arow & 7)) * 8)] = h;\
    }                                                                           \
    _Pragma("unroll")                                                           \
    for (int j = 0; j < 4; ++j) {                                               \
      const int4 q0 = bR[2 * j], q1 = bR[2 * j + 1];                            \
      half8_t h;                                                                \
      h[0] = (_Float16)fmaf((float)q0.x, scR, nzR);                             \
      h[1] = (_Float16)fmaf((float)q0.y, scR, nzR);                             \
      h[2] = (_Float16)fmaf((float)q0.z, scR, nzR);                             \
      h[3] = (_Float16)fmaf((float)q0.w, scR, nzR);                             \
      h[4] = (_Float16)fmaf((float)q1.x, scR, nzR);                             \
      h[5] = (_Float16)fmaf((float)q1.y, scR, nzR);                             \
      h[6] = (_Float16)fmaf((float)q1.z, scR, nzR);                             \
      h[7] = (_Float16)fmaf((float)q1.w, scR, nzR);                             \
      *(half8_t*)&sB[BUF][brow * BK + (((bhalf * 4 + j) ^ (brow & 7)) * 8)] = h;\
    }                                                                           \
  } while (0)

  // One tile: C(T) from buf[cur] | L(T+2) into (aL..) | W(T+1) from (aC..)
  // into buf[nxt]. One lgkmcnt(0)+barrier at the end.
#define TILE(T, aL, bL, scL, nzL, aC, bC, scC, nzC)                             \
  do {                                                                          \
    const _Float16* pA = sA[cur];                                               \
    const _Float16* pB = sB[cur];                                               \
    half8_t fa0[2][2], fa1[2][2], fb[4][2];                                     \
    _Pragma("unroll")                                                           \
    for (int x = 0; x < 2; ++x) {                                               \
      const _Float16* ba = &pA[(wr * 64 + x * 16 + lr) * BK];                   \
      _Pragma("unroll")                                                         \
      for (int ks = 0; ks < 2; ++ks)                                            \
        fa0[x][ks] = *(const half8_t*)&ba[((ks * 4 + quad) ^ (lr & 7)) * 8];    \
    }                                                                           \
    _Pragma("unroll")                                                           \
    for (int ni = 0; ni < 4; ++ni) {                                            \
      const _Float16* bb = &pB[(wc * 64 + ni * 16 + lr) * BK];                  \
      _Pragma("unroll")                                                         \
      for (int ks = 0; ks < 2; ++ks)                                            \
        fb[ni][ks] = *(const half8_t*)&bb[((ks * 4 + quad) ^ (lr & 7)) * 8];    \
    }                                                                           \
    _Pragma("unroll")                                                           \
    for (int x = 0; x < 2; ++x) {                                               \
      const _Float16* ba = &pA[(wr * 64 + (x + 2) * 16 + lr) * BK];             \
      _Pragma("unroll")                                                         \
      for (int ks = 0; ks < 2; ++ks)                                            \
        fa1[x][ks] = *(const half8_t*)&ba[((ks * 4 + quad) ^ (lr & 7)) * 8];    \
    }                                                                           \
    if ((T) + 2 < NTILES) LOADSET((T) + 2, aL, bL, scL, nzL);                   \
    __builtin_amdgcn_sched_barrier(0);                                          \
    if ((T) + 1 < NTILES) WRITESET(nxt, aC, bC, scC, nzC);                      \
    __builtin_amdgcn_s_setprio(1);                                              \
    _Pragma("unroll")                                                           \
    for (int x = 0; x < 2; ++x)                                                 \
      _Pragma("unroll")                                                         \
      for (int ni = 0; ni < 4; ++ni) {                                          \
        acc[x][ni] = __builtin_amdgcn_mfma_f32_16x16x32_f16(fa0[x][0], fb[ni][0], acc[x][ni], 0, 0, 0);         \
        acc[x][ni] = __builtin_amdgcn_mfma_f32_16x16x32_f16(fa0[x][1], fb[ni][1], acc[x][ni], 0, 0, 0);         \
        acc[x + 2][ni] = __builtin_amdgcn_mfma_f32_16x16x32_f16(fa1[x][0], fb[ni][0], acc[x + 2][ni], 0, 0, 0); \
        acc[x + 2][ni] = __builtin_amdgcn_mfma_f32_16x16x32_f16(fa1[x][1], fb[ni][1], acc[x + 2][ni], 0, 0, 0); \
      }                                                                         \
    __builtin_amdgcn_s_setprio(0);                                              \
    asm volatile("s_waitcnt lgkmcnt(0)" ::: "memory");                          \
    __builtin_amdgcn_s_barrier();                                               \
    cur = (cur == 2) ? 0 : cur + 1;                                             \
    nxt = (nxt == 2) ? 0 : nxt + 1;                                             \
  } while (0)

  // Prologue: L(0) -> set0; W(0) -> buf0 (compiler inserts the vmcnt waits);
  // L(1) -> set1; writes drained; barrier.
  LOADSET(0, aR0, bR0, sc0, nz0);
  WRITESET(0, aR0, bR0, sc0, nz0);
  LOADSET(1, aR1, bR1, sc1, nz1);
  asm volatile("s_waitcnt lgkmcnt(0)" ::: "memory");
  __builtin_amdgcn_s_barrier();

  int cur = 0, nxt = 1;
  // Even t: L(t+2)->set0, W(t+1) consumes set1. Odd t: swapped.
  for (int t = 0; t < NTILES; t += 2) {
    TILE(t,     aR0, bR0, sc0, nz0, aR1, bR1, sc1, nz1);
    TILE(t + 1, aR1, bR1, sc1, nz1, aR0, bR0, sc0, nz0);
  }

#undef TILE
#undef WRITESET
#undef LOADSET

  // Epilogue. C/D layout (verified, dtype-independent): col = lane&15,
  // row = quad*4 + reg.
#pragma unroll
  for (int ni = 0; ni < 4; ++ni) {
    const int n = n0 + wc * 64 + ni * 16 + lr;
    const float bv = bias[n];
#pragma unroll
    for (int mi = 0; mi < 4; ++mi) {
      const int mbase = m0 + wr * 64 + mi * 16 + quad * 4;
#pragma unroll
      for (int r = 0; r < 4; ++r)
        out[(size_t)(mbase + r) * NN + n] = acc[mi][ni][r] + bv;
    }
  }
}

extern "C" void kernel_launch(void* const* d_in, const int* in_sizes, int n_in,
                              void* d_out, int out_size, void* d_ws, size_t ws_size,
                              hipStream_t stream) {
  (void)in_sizes; (void)n_in; (void)out_size; (void)d_ws; (void)ws_size;
  const float* A      = (const float*)d_in[0];
  const int*   qw     = (const int*)d_in[1];
  const float* scales = (const float*)d_in[2];
  const float* zeros  = (const float*)d_in[3];
  const float* bias   = (const float*)d_in[4];
  float* out = (float*)d_out;

  // Single fused launch: no prep kernel, no workspace use.
  gemm_fused13<<<dim3(MM / BM * NN / BN), dim3(512), 0, stream>>>(
      A, qw, scales, zeros, bias, out);
}

// Round 8
// 220.156 us; speedup vs baseline: 1.7450x; 1.7450x over previous
//
#include <hip/hip_runtime.h>
#include <cstdint>
#include <cstddef>

// Shapes fixed by the reference harness.
#define MM 2048
#define KK 4096
#define NN 4096
#define GG 32      // K / 128 groups

typedef _Float16 half8_t __attribute__((ext_vector_type(8)));
typedef _Float16 half4_t __attribute__((ext_vector_type(4)));
typedef float f32x4 __attribute__((ext_vector_type(4)));

__device__ __forceinline__ void load_lds16(const void* gptr, void* lptr) {
  // 16B-per-lane direct global->LDS (emits global_load_lds_dwordx4).
  // LDS dest = wave-uniform base + lane*16 (implicit); global source is the
  // per-lane pointer passed.
  __builtin_amdgcn_global_load_lds(
      (const __attribute__((address_space(1))) unsigned int*)gptr,
      (__attribute__((address_space(3))) unsigned int*)lptr, 16, 0, 0);
}

// Merged prep (verified, R6/R7): A fp32->fp16; qweight -> fp16 via
// w = fma(q, s, -z*s). 8 elements/thread.
#define ACNT8 (MM * KK / 8)
__global__ void prep_kernel(const float* __restrict__ A, const int* __restrict__ q,
                            const float* __restrict__ scales, const float* __restrict__ zeros,
                            _Float16* __restrict__ Ah, _Float16* __restrict__ Wh) {
  const int i = blockIdx.x * blockDim.x + threadIdx.x;
  if (i < ACNT8) {
    const float4 v0 = ((const float4*)A)[2 * (size_t)i];
    const float4 v1 = ((const float4*)A)[2 * (size_t)i + 1];
    half8_t h;
    h[0] = (_Float16)v0.x; h[1] = (_Float16)v0.y; h[2] = (_Float16)v0.z; h[3] = (_Float16)v0.w;
    h[4] = (_Float16)v1.x; h[5] = (_Float16)v1.y; h[6] = (_Float16)v1.z; h[7] = (_Float16)v1.w;
    *(half8_t*)(Ah + 8 * (size_t)i) = h;
  } else {
    const int j = i - ACNT8;
    const int e = j << 3;
    const int n = e >> 12;
    const int k = e & (KK - 1);
    const int g = k >> 7;
    const float sc = scales[(n << 5) + g];
    const float zp = zeros[(n << 5) + g];
    const float nzs = -zp * sc;
    const int4 q0 = ((const int4*)q)[2 * (size_t)j];
    const int4 q1 = ((const int4*)q)[2 * (size_t)j + 1];
    half8_t h;
    h[0] = (_Float16)fmaf((float)q0.x, sc, nzs);
    h[1] = (_Float16)fmaf((float)q0.y, sc, nzs);
    h[2] = (_Float16)fmaf((float)q0.z, sc, nzs);
    h[3] = (_Float16)fmaf((float)q0.w, sc, nzs);
    h[4] = (_Float16)fmaf((float)q1.x, sc, nzs);
    h[5] = (_Float16)fmaf((float)q1.y, sc, nzs);
    h[6] = (_Float16)fmaf((float)q1.z, sc, nzs);
    h[7] = (_Float16)fmaf((float)q1.w, sc, nzs);
    *(half8_t*)(Wh + (size_t)e) = h;
  }
}

// ---------------------------------------------------------------------------
// R14 main GEMM: split-K x2 over 256x256 tiles with the m201-class counted-
// vmcnt 2-phase schedule.
//
// WHY: R13 localized the fixed harness residue (~95us); the GEMM itself sits
// at the 2-barrier structure's serial floor (reads 1540cyc + MFMA 1242cyc per
// CU-tile = 74us). The documented escape (256^2 schedule, per-wave 128x64 =
// 25% fewer LDS-read bytes/FLOP + counted-vmcnt phase pipeline, m201/m218)
// needs 256^2 tiles; at M=2048 that is only 128 blocks -> split K in half:
// 256 blocks = {kh} x 8mt x 16nt, each K=2048 (32 BK=64 tiles). kh=0 writes
// out raw; kh=1 writes partial P1 (ws); reduce adds out+P1+bias.
//
// Geometry: 512 thr = 8 waves (2m x 4n), per-wave 128x64 out = acc[8][4]
// f32x4 (128 VGPR). Per tile: a 16 + b 8 = 24 ds_read_b128/wave (vs R7's
// 16 reads for half the MFMA). LDS: 2 buffers x (32KB A + 32KB B) = 128KB.
//
// Ledger (per wave, issue order FIXED): per tile 8 staging calls for t+1,
// split [early6 = A0,A2,B0,B1,B2,B3][late2 = A1,A3]. Early set feeds phase
// one (a-frags mh=0: wr=0->A0, wr=1->A2; all B), late set feeds phase two
// (A1/A3). Steady state:
//   tile t entry (post-barrier): t-early6 landed, t-late2 in flight.
//   phase one:  read a_lo+b; issue t+1 early6 (outstanding 2+6=8);
//               sched_barrier; setprio; 32 MFMA (mf 0..3).
//   mid:        vmcnt(6) -> t-late2 landed; barrier.
//   phase two:  read a_hi; issue t+1 late2 (outstanding 6+2=8);
//               sched_barrier; setprio; 32 MFMA (mf 4..7).
//   boundary:   vmcnt(2) -> t+1-early6 landed; barrier.
// Prologue: issue t0's 8; vmcnt(2); barrier (matches entry state). Tail
// tiles use vmcnt(0). Never drains mid-loop otherwise.
// Buffer safety: tile t reads buf[t&1]; t+1's DMA writes buf[~t&1], whose
// last reader was t-1 (barrier-separated). 
//
// Staging/swizzle/frag-reads/C-D layout: verified R7 components unchanged
// (phys 16B chunk p of row r holds logical p^(r&7); gch=(lane&7)^(lane>>3);
// reads j^(lr&7); row&7==lr&7 since all row offsets are multiples of 8/16).
// ---------------------------------------------------------------------------
#define KTILES 32   // per K-half
__global__ __launch_bounds__(512)
void gemm16_kernel(const _Float16* __restrict__ Ah, const _Float16* __restrict__ Wh,
                   float* __restrict__ out, float* __restrict__ P1)
{
  __shared__ __align__(16) _Float16 sA[2][256 * 64];   // 2 x 32 KiB
  __shared__ __align__(16) _Float16 sB[2][256 * 64];   // 2 x 32 KiB

  const int tid = threadIdx.x;
  const int lane = tid & 63;
  const int wave = tid >> 6;        // 0..7
  const int wr = wave >> 2;         // 0..1  m-half (128 rows)
  const int wc = wave & 3;          // 0..3  n-quarter (64 cols)
  const int lr = lane & 15, quad = lane >> 4;

  // Block map: xcd = bid&7 owns mt = xcd (A-panel locality per XCD-L2);
  // slot = bid>>3 in 0..31: kh = slot>>4, nt = slot&15.
  const int bid = blockIdx.x;
  const int xcd = bid & 7;
  const int slot = bid >> 3;
  const int kh = slot >> 4;         // 0..1 K-half
  const int nt = slot & 15;         // 0..15
  const int m0 = xcd * 256;
  const int n0 = nt * 256;
  const int khBase = kh * (KK / 2);

  const int srow = lane >> 3, scc = lane & 7, gch = scc ^ srow;

  f32x4 acc[8][4];
#pragma unroll
  for (int i = 0; i < 8; ++i)
#pragma unroll
    for (int j = 0; j < 4; ++j) acc[i][j] = (f32x4){0.f, 0.f, 0.f, 0.f};

  // Staging: call c covers rows c*64 + wave*8 + srow (8 waves x 8 rows).
  auto stA = [&](int t, int buf, int c) {
    load_lds16(Ah + (size_t)(m0 + c * 64 + (wave << 3) + srow) * KK + khBase + t * 64 + (gch << 3),
               (void*)&sA[buf][(c * 64 + (wave << 3)) * 64]);
  };
  auto stB = [&](int t, int buf, int c) {
    load_lds16(Wh + (size_t)(n0 + c * 64 + (wave << 3) + srow) * KK + khBase + t * 64 + (gch << 3),
               (void*)&sB[buf][(c * 64 + (wave << 3)) * 64]);
  };
  // Issue-order macros (vmcnt counts a wave's own issues in order).
#define EARLY6(T, BUF) do { stA((T), (BUF), 0); stA((T), (BUF), 2); \
    stB((T), (BUF), 0); stB((T), (BUF), 1); stB((T), (BUF), 2); stB((T), (BUF), 3); } while (0)
#define LATE2(T, BUF)  do { stA((T), (BUF), 1); stA((T), (BUF), 3); } while (0)

  // Prologue: tile 0's 8 calls; early6 landed, late2 in flight.
  EARLY6(0, 0); LATE2(0, 0);
  asm volatile("s_waitcnt vmcnt(2)" ::: "memory");
  __builtin_amdgcn_s_barrier();

  for (int t = 0; t < KTILES; ++t) {
    const int bufc = t & 1, bufn = bufc ^ 1;
    const _Float16* pA = sA[bufc];
    const _Float16* pB = sB[bufc];
    const bool more = (t + 1 < KTILES);   // uniform

    half8_t a[4][2], b[4][2];
    // ---- phase one: a-frags mf 0..3 (rows wr*128 + mf*16, inside A0/A2) +
    //      all b-frags; 32 MFMA ----
#pragma unroll
    for (int mf = 0; mf < 4; ++mf) {
      const _Float16* ba = &pA[(wr * 128 + mf * 16 + lr) * 64];
#pragma unroll
      for (int ks = 0; ks < 2; ++ks)
        a[mf][ks] = *(const half8_t*)&ba[((ks * 4 + quad) ^ (lr & 7)) * 8];
    }
#pragma unroll
    for (int nf = 0; nf < 4; ++nf) {
      const _Float16* bb = &pB[(wc * 64 + nf * 16 + lr) * 64];
#pragma unroll
      for (int ks = 0; ks < 2; ++ks)
        b[nf][ks] = *(const half8_t*)&bb[((ks * 4 + quad) ^ (lr & 7)) * 8];
    }
    if (more) EARLY6(t + 1, bufn);
    __builtin_amdgcn_sched_barrier(0);
    __builtin_amdgcn_s_setprio(1);
#pragma unroll
    for (int mf = 0; mf < 4; ++mf)
#pragma unroll
      for (int nf = 0; nf < 4; ++nf) {
        acc[mf][nf] = __builtin_amdgcn_mfma_f32_16x16x32_f16(a[mf][0], b[nf][0], acc[mf][nf], 0, 0, 0);
        acc[mf][nf] = __builtin_amdgcn_mfma_f32_16x16x32_f16(a[mf][1], b[nf][1], acc[mf][nf], 0, 0, 0);
      }
    __builtin_amdgcn_s_setprio(0);

    // mid: this tile's late2 (A1/A3) must land; t+1's early6 stays in flight.
    if (more) asm volatile("s_waitcnt vmcnt(6)" ::: "memory");
    else      asm volatile("s_waitcnt vmcnt(0)" ::: "memory");
    __builtin_amdgcn_s_barrier();

    // ---- phase two: a-frags mf 4..7 (rows inside A1/A3); b reused ----
    half8_t ah[4][2];
#pragma unroll
    for (int mf = 0; mf < 4; ++mf) {
      const _Float16* ba = &pA[(wr * 128 + (mf + 4) * 16 + lr) * 64];
#pragma unroll
      for (int ks = 0; ks < 2; ++ks)
        ah[mf][ks] = *(const half8_t*)&ba[((ks * 4 + quad) ^ (lr & 7)) * 8];
    }
    if (more) LATE2(t + 1, bufn);
    __builtin_amdgcn_sched_barrier(0);
    __builtin_amdgcn_s_setprio(1);
#pragma unroll
    for (int mf = 0; mf < 4; ++mf)
#pragma unroll
      for (int nf = 0; nf < 4; ++nf) {
        acc[mf + 4][nf] = __builtin_amdgcn_mfma_f32_16x16x32_f16(ah[mf][0], b[nf][0], acc[mf + 4][nf], 0, 0, 0);
        acc[mf + 4][nf] = __builtin_amdgcn_mfma_f32_16x16x32_f16(ah[mf][1], b[nf][1], acc[mf + 4][nf], 0, 0, 0);
      }
    __builtin_amdgcn_s_setprio(0);

    // boundary: t+1's early6 landed; its late2 stays in flight.
    if (more) asm volatile("s_waitcnt vmcnt(2)" ::: "memory");
    else      asm volatile("s_waitcnt vmcnt(0)" ::: "memory");
    __builtin_amdgcn_s_barrier();
  }

#undef EARLY6
#undef LATE2

  // Epilogue: raw partial (bias added in reduce). C/D layout (verified):
  // col = lane&15, row = quad*4 + reg.
  float* dst = (kh == 0) ? out : P1;
#pragma unroll
  for (int nf = 0; nf < 4; ++nf) {
    const int n = n0 + wc * 64 + nf * 16 + lr;
#pragma unroll
    for (int mf = 0; mf < 8; ++mf) {
      const int mbase = m0 + wr * 128 + mf * 16 + quad * 4;
#pragma unroll
      for (int r = 0; r < 4; ++r)
        dst[(size_t)(mbase + r) * NN + n] = acc[mf][nf][r];
    }
  }
}

// out = out + P1 + bias (vectorized f32x4).
__global__ void reduce_kernel(float* __restrict__ out, const float* __restrict__ P1,
                              const float* __restrict__ bias) {
  const int i = blockIdx.x * blockDim.x + threadIdx.x;   // f32x4 index
  const int n = (i * 4) & (NN - 1);
  const float4 o = ((const float4*)out)[i];
  const float4 p = ((const float4*)P1)[i];
  const float4 b = *(const float4*)&bias[n];
  float4 r;
  r.x = o.x + p.x + b.x; r.y = o.y + p.y + b.y;
  r.z = o.z + p.z + b.z; r.w = o.w + p.w + b.w;
  ((float4*)out)[i] = r;
}

// ---------------------------------------------------------------------------
// Fallback 1 (ws >= 48MB only): R7's verified 79.6us kernel, verbatim.
// ---------------------------------------------------------------------------
__global__ __launch_bounds__(512, 2)
void gemm8_kernel(const _Float16* __restrict__ Ah, const _Float16* __restrict__ Wh,
                  const float* __restrict__ bias, float* __restrict__ out)
{
  __shared__ __align__(16) _Float16 sA[3][128 * 64];
  __shared__ __align__(16) _Float16 sB[3][256 * 64];

  const int tid = threadIdx.x;
  const int lane = tid & 63;
  const int wave = tid >> 6;
  const int wr = wave >> 2;
  const int wc = wave & 3;
  const int lr = lane & 15, quad = lane >> 4;

  const int bid = blockIdx.x;
  const int xcd = bid & 7;
  const int slot = bid >> 3;
  const int mt = slot >> 1;
  const int nt = xcd * 2 + (slot & 1);
  const int m0 = mt * 128;
  const int n0 = nt * 256;

  const int srow = lane >> 3, scc = lane & 7, gch = scc ^ srow;

  f32x4 acc[4][4];
#pragma unroll
  for (int i = 0; i < 4; ++i)
#pragma unroll
    for (int j = 0; j < 4; ++j) acc[i][j] = (f32x4){0.f, 0.f, 0.f, 0.f};

  auto stageA = [&](int t, int buf, int i) {
    load_lds16(Ah + (size_t)(m0 + i * 64 + (wave << 3) + srow) * KK + t * 64 + (gch << 3),
               (void*)&sA[buf][(i * 64 + (wave << 3)) * 64]);
  };
  auto stageB = [&](int t, int buf, int i) {
    load_lds16(Wh + (size_t)(n0 + i * 64 + (wave << 3) + srow) * KK + t * 64 + (gch << 3),
               (void*)&sB[buf][(i * 64 + (wave << 3)) * 64]);
  };

  stageB(0, 0, 0); stageB(0, 0, 1); stageA(0, 0, 0);
  stageB(0, 0, 2); stageB(0, 0, 3); stageA(0, 0, 1);
  stageB(1, 1, 0); stageB(1, 1, 1); stageA(1, 1, 0);
  stageB(1, 1, 2); stageB(1, 1, 3); stageA(1, 1, 1);
  asm volatile("s_waitcnt vmcnt(6)" ::: "memory");
  __builtin_amdgcn_s_barrier();

  int cur = 0, nb = 2;
  for (int t = 0; t < 64; ++t) {
    const _Float16* pA = sA[cur];
    const _Float16* pB = sB[cur];
    const bool st = (t < 62);
    half8_t a0[2][2], a1[2][2], b[4][2];

#pragma unroll
    for (int x = 0; x < 2; ++x) {
      const _Float16* ba = &pA[(wr * 64 + x * 16 + lr) * 64];
#pragma unroll
      for (int ks = 0; ks < 2; ++ks)
        a0[x][ks] = *(const half8_t*)&ba[((ks * 4 + quad) ^ (lr & 7)) * 8];
    }
#pragma unroll
    for (int ni = 0; ni < 4; ++ni) {
      const _Float16* bb = &pB[(wc * 64 + ni * 16 + lr) * 64];
#pragma unroll
      for (int ks = 0; ks < 2; ++ks)
        b[ni][ks] = *(const half8_t*)&bb[((ks * 4 + quad) ^ (lr & 7)) * 8];
    }
    if (st) { stageB(t + 2, nb, 0); stageB(t + 2, nb, 1); stageA(t + 2, nb, 0); }
    __builtin_amdgcn_sched_barrier(0);
    __builtin_amdgcn_s_barrier();
    __builtin_amdgcn_s_setprio(1);
#pragma unroll
    for (int x = 0; x < 2; ++x)
#pragma unroll
      for (int ni = 0; ni < 4; ++ni) {
        acc[x][ni] = __builtin_amdgcn_mfma_f32_16x16x32_f16(a0[x][0], b[ni][0], acc[x][ni], 0, 0, 0);
        acc[x][ni] = __builtin_amdgcn_mfma_f32_16x16x32_f16(a0[x][1], b[ni][1], acc[x][ni], 0, 0, 0);
      }
    __builtin_amdgcn_s_setprio(0);
    __builtin_amdgcn_s_barrier();

#pragma unroll
    for (int x = 0; x < 2; ++x) {
      const _Float16* ba = &pA[(wr * 64 + (x + 2) * 16 + lr) * 64];
#pragma unroll
      for (int ks = 0; ks < 2; ++ks)
        a1[x][ks] = *(const half8_t*)&ba[((ks * 4 + quad) ^ (lr & 7)) * 8];
    }
    if (st) { stageB(t + 2, nb, 2); stageB(t + 2, nb, 3); stageA(t + 2, nb, 1); }
    __builtin_amdgcn_sched_barrier(0);
    __builtin_amdgcn_s_barrier();
    __builtin_amdgcn_s_setprio(1);
#pragma unroll
    for (int x = 0; x < 2; ++x)
#pragma unroll
      for (int ni = 0; ni < 4; ++ni) {
        acc[x + 2][ni] = __builtin_amdgcn_mfma_f32_16x16x32_f16(a1[x][0], b[ni][0], acc[x + 2][ni], 0, 0, 0);
        acc[x + 2][ni] = __builtin_amdgcn_mfma_f32_16x16x32_f16(a1[x][1], b[ni][1], acc[x + 2][ni], 0, 0, 0);
      }
    __builtin_amdgcn_s_setprio(0);
    if (t < 62) asm volatile("s_waitcnt vmcnt(6)" ::: "memory");
    else        asm volatile("s_waitcnt vmcnt(0)" ::: "memory");
    __builtin_amdgcn_s_barrier();
    cur = (cur == 2) ? 0 : cur + 1;
    nb  = (nb  == 2) ? 0 : nb + 1;
  }

#pragma unroll
  for (int ni = 0; ni < 4; ++ni) {
    const int n = n0 + wc * 64 + ni * 16 + lr;
    const float bv = bias[n];
#pragma unroll
    for (int mi = 0; mi < 4; ++mi) {
      const int mbase = m0 + wr * 64 + mi * 16 + quad * 4;
#pragma unroll
      for (int r = 0; r < 4; ++r)
        out[(size_t)(mbase + r) * NN + n] = acc[mi][ni][r] + bv;
    }
  }
}

// Fallback 2 (no ws): verified self-contained fused-dequant kernel (R6).
__global__ __launch_bounds__(256, 2)
void gemm_fused_kernel(const float* __restrict__ Af, const int* __restrict__ qw,
                       const float* __restrict__ scales, const float* __restrict__ zeros,
                       const float* __restrict__ bias, float* __restrict__ out)
{
  __shared__ __align__(16) _Float16 sA[128 * 64];
  __shared__ __align__(16) _Float16 sB[128 * 64];

  const int tid = threadIdx.x;
  const int lane = tid & 63;
  const int wave = tid >> 6;
  const int wr = wave >> 1, wc = wave & 1;

  const int bid = blockIdx.x;
  const int xcd = bid & 7;
  const int slot = bid >> 3;
  const int mt = slot >> 2;
  const int nt = xcd * 4 + (slot & 3);
  const int m0 = mt * 128;
  const int n0 = nt * 128;

  const int lr = lane & 15, quad = lane >> 4;

  f32x4 acc[4][4];
#pragma unroll
  for (int i = 0; i < 4; ++i)
#pragma unroll
    for (int j = 0; j < 4; ++j) acc[i][j] = (f32x4){0.f, 0.f, 0.f, 0.f};

  const int frow = tid >> 4;
  const int fc4 = tid & 15;

  for (int kt = 0; kt < KK / 64; ++kt) {
    const int k0 = kt * 64;
    const int g = k0 >> 7;
#pragma unroll
    for (int p = 0; p < 8; ++p) {
      const int row = p * 16 + frow;
      const int pc = (fc4 >> 1) ^ (row & 7);
      const int dst = row * 64 + pc * 8 + (fc4 & 1) * 4;
      const float4 avf = *(const float4*)&Af[(size_t)(m0 + row) * KK + k0 + fc4 * 4];
      half4_t ah;
      ah[0] = (_Float16)avf.x; ah[1] = (_Float16)avf.y;
      ah[2] = (_Float16)avf.z; ah[3] = (_Float16)avf.w;
      *(half4_t*)&sA[dst] = ah;
      const int n = n0 + row;
      const float sc = scales[(n << 5) + g];
      const float zp = zeros[(n << 5) + g];
      const float nzs = -zp * sc;
      const int4 qv = *(const int4*)&qw[(size_t)n * KK + k0 + fc4 * 4];
      half4_t bh;
      bh[0] = (_Float16)fmaf((float)qv.x, sc, nzs);
      bh[1] = (_Float16)fmaf((float)qv.y, sc, nzs);
      bh[2] = (_Float16)fmaf((float)qv.z, sc, nzs);
      bh[3] = (_Float16)fmaf((float)qv.w, sc, nzs);
      *(half4_t*)&sB[dst] = bh;
    }
    __syncthreads();
#pragma unroll
    for (int ks = 0; ks < 2; ++ks) {
      half8_t a[4], b[4];
#pragma unroll
      for (int t = 0; t < 4; ++t) {
        const int rA = wr * 64 + t * 16 + lr;
        const int j = ks * 4 + quad;
        a[t] = *(const half8_t*)&sA[rA * 64 + ((j ^ (lr & 7)) * 8)];
        const int rB = wc * 64 + t * 16 + lr;
        b[t] = *(const half8_t*)&sB[rB * 64 + ((j ^ (lr & 7)) * 8)];
      }
#pragma unroll
      for (int mi = 0; mi < 4; ++mi)
#pragma unroll
        for (int ni = 0; ni < 4; ++ni)
          acc[mi][ni] = __builtin_amdgcn_mfma_f32_16x16x32_f16(a[mi], b[ni], acc[mi][ni], 0, 0, 0);
    }
    __syncthreads();
  }

#pragma unroll
  for (int ni = 0; ni < 4; ++ni) {
    const int n = n0 + wc * 64 + ni * 16 + lr;
    const float bv = bias[n];
#pragma unroll
    for (int mi = 0; mi < 4; ++mi) {
      const int mbase = m0 + wr * 64 + mi * 16 + quad * 4;
#pragma unroll
      for (int r = 0; r < 4; ++r)
        out[(size_t)(mbase + r) * NN + n] = acc[mi][ni][r] + bv;
    }
  }
}

extern "C" void kernel_launch(void* const* d_in, const int* in_sizes, int n_in,
                              void* d_out, int out_size, void* d_ws, size_t ws_size,
                              hipStream_t stream) {
  (void)in_sizes; (void)n_in; (void)out_size;
  const float* A      = (const float*)d_in[0];
  const int*   qw     = (const int*)d_in[1];
  const float* scales = (const float*)d_in[2];
  const float* zeros  = (const float*)d_in[3];
  const float* bias   = (const float*)d_in[4];
  float* out = (float*)d_out;

  const size_t needA = (size_t)MM * KK * sizeof(_Float16);  // 16 MB
  const size_t needW = (size_t)NN * KK * sizeof(_Float16);  // 32 MB
  const size_t needP = (size_t)MM * NN * sizeof(float);     // 32 MB

  if (ws_size >= needA + needW + needP) {
    _Float16* Ah = (_Float16*)d_ws;
    _Float16* Wh = (_Float16*)((char*)d_ws + needA);
    float*    P1 = (float*)((char*)d_ws + needA + needW);
    prep_kernel<<<((MM + NN) * KK / 8) / 256, 256, 0, stream>>>(A, qw, scales, zeros, Ah, Wh);
    gemm16_kernel<<<dim3(256), dim3(512), 0, stream>>>(Ah, Wh, out, P1);
    reduce_kernel<<<dim3(MM * NN / 4 / 256), dim3(256), 0, stream>>>(out, P1, bias);
  } else if (ws_size >= needA + needW) {
    _Float16* Ah = (_Float16*)d_ws;
    _Float16* Wh = (_Float16*)((char*)d_ws + needA);
    prep_kernel<<<((MM + NN) * KK / 8) / 256, 256, 0, stream>>>(A, qw, scales, zeros, Ah, Wh);
    gemm8_kernel<<<dim3(256), dim3(512), 0, stream>>>(Ah, Wh, bias, out);
  } else {
    gemm_fused_kernel<<<dim3(512), dim3(256), 0, stream>>>(A, qw, scales, zeros, bias, out);
  }
}